// Round 1
// baseline (1324.231 us; speedup 1.0000x reference)
//
#include <hip/hip_runtime.h>

#define N_NODES 100000
#define OUT_C   128   // 64 lanes * float2

// ---------------- CSR build ----------------

__global__ void zero_int_kernel(int* __restrict__ p, int n) {
    int i = blockIdx.x * blockDim.x + threadIdx.x;
    if (i < n) p[i] = 0;
}

__global__ void count_rows_kernel(const int* __restrict__ rows, int* __restrict__ counts, int nnz) {
    int i = blockIdx.x * blockDim.x + threadIdx.x;
    if (i < nnz) atomicAdd(&counts[rows[i]], 1);
}

// Single block, 1024 threads. counts may alias cursor (we read counts[i] before
// writing cursor[i], and threads only touch their own chunk outside the LDS scan).
__global__ void scan_counts_kernel(const int* counts, int* row_ptr, int* cursor, int n) {
    __shared__ int part[1024];
    const int t = threadIdx.x;
    const int chunk = (n + 1023) >> 10;
    const int beg = t * chunk;
    const int end = min(beg + chunk, n);
    int s = 0;
    for (int i = beg; i < end; ++i) s += counts[i];
    part[t] = s;
    __syncthreads();
    // Hillis-Steele inclusive scan over 1024 partials
    for (int off = 1; off < 1024; off <<= 1) {
        int v = (t >= off) ? part[t - off] : 0;
        __syncthreads();
        part[t] += v;
        __syncthreads();
    }
    int run = (t == 0) ? 0 : part[t - 1];   // exclusive prefix for this chunk
    for (int i = beg; i < end; ++i) {
        int c = counts[i];          // read BEFORE writing cursor[i] (aliasing-safe)
        row_ptr[i] = run;
        cursor[i]  = run;
        run += c;
    }
    if (t == 1023) row_ptr[n] = part[1023];
}

__global__ void scatter_coo_kernel(const int* __restrict__ rows, const int* __restrict__ cols,
                                   const float* __restrict__ vals, int* __restrict__ cursor,
                                   int* __restrict__ csr_col, float* __restrict__ csr_val, int nnz) {
    int i = blockIdx.x * blockDim.x + threadIdx.x;
    if (i < nnz) {
        int p = atomicAdd(&cursor[rows[i]], 1);
        csr_col[p] = cols[i];
        csr_val[p] = vals[i];
    }
}

// ---------------- SpMM: sparse [N, IN_C] @ dense weight [IN_C, 128] + bias + relu ----------------
// One 64-lane wave per output row; each lane owns a float2 slice of the 128 outputs.

__global__ __launch_bounds__(256) void spmm_feat_kernel(
        const int* __restrict__ row_ptr, const int* __restrict__ csr_col,
        const float* __restrict__ csr_val, const float* __restrict__ W,
        const float* __restrict__ bias, float* __restrict__ out, int n) {
    const int wave = (blockIdx.x * blockDim.x + threadIdx.x) >> 6;
    const int lane = threadIdx.x & 63;
    if (wave >= n) return;
    const int beg = row_ptr[wave];
    const int end = row_ptr[wave + 1];
    const float2* __restrict__ W2 = (const float2*)W;
    float2 acc = make_float2(0.f, 0.f);
    for (int i = beg; i < end; ++i) {
        const int   c = csr_col[i];
        const float v = csr_val[i];
        const float2 w = W2[c * 64 + lane];
        acc.x += v * w.x;
        acc.y += v * w.y;
    }
    const float2 b = ((const float2*)bias)[lane];
    acc.x = fmaxf(acc.x + b.x, 0.f);
    acc.y = fmaxf(acc.y + b.y, 0.f);
    ((float2*)out)[wave * 64 + lane] = acc;
}

// ---------------- adjacency propagation: dst = A @ src ----------------

__global__ __launch_bounds__(256) void spmm_adj_kernel(
        const int* __restrict__ row_ptr, const int* __restrict__ csr_col,
        const float* __restrict__ csr_val, const float* __restrict__ src,
        float* __restrict__ dst, int n) {
    const int wave = (blockIdx.x * blockDim.x + threadIdx.x) >> 6;
    const int lane = threadIdx.x & 63;
    if (wave >= n) return;
    const int beg = row_ptr[wave];
    const int end = row_ptr[wave + 1];
    const float2* __restrict__ S2 = (const float2*)src;
    float2 acc = make_float2(0.f, 0.f);
    for (int i = beg; i < end; ++i) {
        const int   c = csr_col[i];
        const float w = csr_val[i];
        const float2 s = S2[c * 64 + lane];
        acc.x += w * s.x;
        acc.y += w * s.y;
    }
    ((float2*)dst)[wave * 64 + lane] = acc;
}

// ---------------- launch ----------------

extern "C" void kernel_launch(void* const* d_in, const int* in_sizes, int n_in,
                              void* d_out, int out_size, void* d_ws, size_t ws_size,
                              hipStream_t stream) {
    const int*   fi   = (const int*)d_in[0];     // feat_indices [2, nnzf]
    const float* fv   = (const float*)d_in[1];   // feat_values  [nnzf]
    const int*   ai   = (const int*)d_in[2];     // adj_indices  [2, nedge]
    const float* av   = (const float*)d_in[3];   // adj_values   [nedge]
    const float* W    = (const float*)d_in[4];   // weight [512,128]
    const float* bias = (const float*)d_in[5];   // bias [1,128]
    float* out = (float*)d_out;

    const int nnzf  = in_sizes[1];
    const int nedge = in_sizes[3];
    const int* f_rows = fi;
    const int* f_cols = fi + nnzf;
    const int* a_rows = ai;
    const int* a_cols = ai + nedge;

    // bump-allocate workspace (256B aligned)
    char* wp = (char*)d_ws;
    auto balloc = [&](size_t bytes) -> char* {
        char* p = wp;
        wp += (bytes + 255) & ~(size_t)255;
        return p;
    };
    float* base_ws = (float*)balloc(sizeof(float) * (size_t)N_NODES * OUT_C);
    int*   f_rp    = (int*)balloc(4 * (size_t)(N_NODES + 1));
    int*   f_cur   = (int*)balloc(4 * (size_t)N_NODES);
    int*   f_ccol  = (int*)balloc(4 * (size_t)nnzf);
    float* f_cval  = (float*)balloc(4 * (size_t)nnzf);
    int*   a_rp    = (int*)balloc(4 * (size_t)(N_NODES + 1));
    int*   a_cur   = (int*)balloc(4 * (size_t)N_NODES);
    int*   a_ccol  = (int*)balloc(4 * (size_t)nedge);
    float* a_cval  = (float*)balloc(4 * (size_t)nedge);

    const int ZB = (N_NODES + 255) / 256;
    const int FB = (nnzf + 255) / 256;
    const int AB = (nedge + 255) / 256;
    const int RW = (N_NODES + 3) / 4;    // 4 waves (rows) per 256-thread block

    // ---- feature CSR ----
    zero_int_kernel<<<ZB, 256, 0, stream>>>(f_cur, N_NODES);
    count_rows_kernel<<<FB, 256, 0, stream>>>(f_rows, f_cur, nnzf);
    scan_counts_kernel<<<1, 1024, 0, stream>>>(f_cur, f_rp, f_cur, N_NODES);
    scatter_coo_kernel<<<FB, 256, 0, stream>>>(f_rows, f_cols, fv, f_cur, f_ccol, f_cval, nnzf);

    // ---- adjacency CSR ----
    zero_int_kernel<<<ZB, 256, 0, stream>>>(a_cur, N_NODES);
    count_rows_kernel<<<AB, 256, 0, stream>>>(a_rows, a_cur, nedge);
    scan_counts_kernel<<<1, 1024, 0, stream>>>(a_cur, a_rp, a_cur, N_NODES);
    scatter_coo_kernel<<<AB, 256, 0, stream>>>(a_rows, a_cols, av, a_cur, a_ccol, a_cval, nedge);

    // ---- compute: spmm -> d_out, adj -> ws, adj -> d_out ----
    spmm_feat_kernel<<<RW, 256, 0, stream>>>(f_rp, f_ccol, f_cval, W, bias, out, N_NODES);
    spmm_adj_kernel<<<RW, 256, 0, stream>>>(a_rp, a_ccol, a_cval, out, base_ws, N_NODES);
    spmm_adj_kernel<<<RW, 256, 0, stream>>>(a_rp, a_ccol, a_cval, base_ws, out, N_NODES);
}

// Round 2
// 774.347 us; speedup vs baseline: 1.7101x; 1.7101x over previous
//
#include <hip/hip_runtime.h>

#define N_NODES 100000
#define OUT_C   128   // 64 lanes * float2

#define SCAN_T     256
#define SCAN_ITEMS 8
#define SCAN_CHUNK (SCAN_T * SCAN_ITEMS)   // 2048 elems per block

// ---------------- CSR build ----------------

__global__ void zero_int_kernel(int* __restrict__ p, int n) {
    int i = blockIdx.x * blockDim.x + threadIdx.x;
    if (i < n) p[i] = 0;
}

__global__ void count_rows_kernel(const int* __restrict__ rows, int* __restrict__ counts, int nnz) {
    int i = blockIdx.x * blockDim.x + threadIdx.x;
    if (i < nnz) atomicAdd(&counts[rows[i]], 1);
}

// Pass 1: per-block sums of counts (each thread owns SCAN_ITEMS contiguous elems)
__global__ __launch_bounds__(SCAN_T) void scan_blocksums_kernel(
        const int* __restrict__ counts, int* __restrict__ blk, int n) {
    __shared__ int red[SCAN_T];
    const int t = threadIdx.x;
    const int base = blockIdx.x * SCAN_CHUNK + t * SCAN_ITEMS;
    int s = 0;
    #pragma unroll
    for (int k = 0; k < SCAN_ITEMS; ++k) {
        int idx = base + k;
        if (idx < n) s += counts[idx];
    }
    red[t] = s;
    __syncthreads();
    for (int off = SCAN_T / 2; off > 0; off >>= 1) {
        if (t < off) red[t] += red[t + off];
        __syncthreads();
    }
    if (t == 0) blk[blockIdx.x] = red[0];
}

// Pass 2: single small block — exclusive scan of the <=1024 block sums in place;
// also writes row_ptr[n] = grand total.
__global__ void scan_toplevel_kernel(int* __restrict__ blk, int nb,
                                     int* __restrict__ row_ptr, int n) {
    __shared__ int sh[1024];
    const int t = threadIdx.x;
    int v = (t < nb) ? blk[t] : 0;
    sh[t] = v;
    __syncthreads();
    for (int off = 1; off < 1024; off <<= 1) {
        int u = (t >= off) ? sh[t - off] : 0;
        __syncthreads();
        sh[t] += u;
        __syncthreads();
    }
    if (t < nb) blk[t] = sh[t] - v;         // exclusive prefix
    if (t == 1023) row_ptr[n] = sh[1023];   // grand total
}

// Pass 3: per-block exclusive scan + global offset; writes row_ptr and cursor.
// counts may alias cursor: each idx is read (counts) then written (cursor) by the
// same thread, and no other thread touches it.
__global__ __launch_bounds__(SCAN_T) void scan_final_kernel(
        const int* __restrict__ counts, const int* __restrict__ blk,
        int* __restrict__ row_ptr, int* __restrict__ cursor, int n) {
    __shared__ int sh[SCAN_T];
    const int t = threadIdx.x;
    const int base = blockIdx.x * SCAN_CHUNK + t * SCAN_ITEMS;
    int loc[SCAN_ITEMS];
    int s = 0;
    #pragma unroll
    for (int k = 0; k < SCAN_ITEMS; ++k) {
        int idx = base + k;
        int c = (idx < n) ? counts[idx] : 0;
        loc[k] = s;                 // exclusive within-thread prefix
        s += c;
    }
    sh[t] = s;
    __syncthreads();
    for (int off = 1; off < SCAN_T; off <<= 1) {
        int u = (t >= off) ? sh[t - off] : 0;
        __syncthreads();
        sh[t] += u;
        __syncthreads();
    }
    const int thread_off = blk[blockIdx.x] + ((t == 0) ? 0 : sh[t - 1]);
    #pragma unroll
    for (int k = 0; k < SCAN_ITEMS; ++k) {
        int idx = base + k;
        if (idx < n) {
            int p = thread_off + loc[k];
            row_ptr[idx] = p;
            cursor[idx]  = p;
        }
    }
}

__global__ void scatter_coo_kernel(const int* __restrict__ rows, const int* __restrict__ cols,
                                   const float* __restrict__ vals, int* __restrict__ cursor,
                                   int* __restrict__ csr_col, float* __restrict__ csr_val, int nnz) {
    int i = blockIdx.x * blockDim.x + threadIdx.x;
    if (i < nnz) {
        int p = atomicAdd(&cursor[rows[i]], 1);
        csr_col[p] = cols[i];
        csr_val[p] = vals[i];
    }
}

// ---------------- SpMM: sparse [N, IN_C] @ dense weight [IN_C, 128] + bias + relu ----------------
// One 64-lane wave per output row; each lane owns a float2 slice of the 128 outputs.
// 4-way unrolled: 4 independent gather chains per iteration for MLP.

__global__ __launch_bounds__(256) void spmm_feat_kernel(
        const int* __restrict__ row_ptr, const int* __restrict__ csr_col,
        const float* __restrict__ csr_val, const float* __restrict__ W,
        const float* __restrict__ bias, float* __restrict__ out, int n) {
    const int wave = (blockIdx.x * blockDim.x + threadIdx.x) >> 6;
    const int lane = threadIdx.x & 63;
    if (wave >= n) return;
    const int beg = row_ptr[wave];
    const int end = row_ptr[wave + 1];
    const float2* __restrict__ W2 = (const float2*)W;
    float2 a0 = make_float2(0.f, 0.f), a1 = a0, a2 = a0, a3 = a0;
    int i = beg;
    for (; i + 3 < end; i += 4) {
        const int c0 = csr_col[i],     c1 = csr_col[i + 1];
        const int c2 = csr_col[i + 2], c3 = csr_col[i + 3];
        const float v0 = csr_val[i],     v1 = csr_val[i + 1];
        const float v2 = csr_val[i + 2], v3 = csr_val[i + 3];
        const float2 w0 = W2[c0 * 64 + lane];
        const float2 w1 = W2[c1 * 64 + lane];
        const float2 w2 = W2[c2 * 64 + lane];
        const float2 w3 = W2[c3 * 64 + lane];
        a0.x += v0 * w0.x; a0.y += v0 * w0.y;
        a1.x += v1 * w1.x; a1.y += v1 * w1.y;
        a2.x += v2 * w2.x; a2.y += v2 * w2.y;
        a3.x += v3 * w3.x; a3.y += v3 * w3.y;
    }
    for (; i < end; ++i) {
        const int   c = csr_col[i];
        const float v = csr_val[i];
        const float2 w = W2[c * 64 + lane];
        a0.x += v * w.x; a0.y += v * w.y;
    }
    const float2 b = ((const float2*)bias)[lane];
    float2 acc;
    acc.x = fmaxf((a0.x + a1.x) + (a2.x + a3.x) + b.x, 0.f);
    acc.y = fmaxf((a0.y + a1.y) + (a2.y + a3.y) + b.y, 0.f);
    ((float2*)out)[wave * 64 + lane] = acc;
}

// ---------------- adjacency propagation: dst = A @ src ----------------

__global__ __launch_bounds__(256) void spmm_adj_kernel(
        const int* __restrict__ row_ptr, const int* __restrict__ csr_col,
        const float* __restrict__ csr_val, const float* __restrict__ src,
        float* __restrict__ dst, int n) {
    const int wave = (blockIdx.x * blockDim.x + threadIdx.x) >> 6;
    const int lane = threadIdx.x & 63;
    if (wave >= n) return;
    const int beg = row_ptr[wave];
    const int end = row_ptr[wave + 1];
    const float2* __restrict__ S2 = (const float2*)src;
    float2 a0 = make_float2(0.f, 0.f), a1 = a0, a2 = a0, a3 = a0;
    int i = beg;
    for (; i + 3 < end; i += 4) {
        const int c0 = csr_col[i],     c1 = csr_col[i + 1];
        const int c2 = csr_col[i + 2], c3 = csr_col[i + 3];
        const float v0 = csr_val[i],     v1 = csr_val[i + 1];
        const float v2 = csr_val[i + 2], v3 = csr_val[i + 3];
        const float2 s0 = S2[c0 * 64 + lane];
        const float2 s1 = S2[c1 * 64 + lane];
        const float2 s2 = S2[c2 * 64 + lane];
        const float2 s3 = S2[c3 * 64 + lane];
        a0.x += v0 * s0.x; a0.y += v0 * s0.y;
        a1.x += v1 * s1.x; a1.y += v1 * s1.y;
        a2.x += v2 * s2.x; a2.y += v2 * s2.y;
        a3.x += v3 * s3.x; a3.y += v3 * s3.y;
    }
    for (; i < end; ++i) {
        const int   c = csr_col[i];
        const float w = csr_val[i];
        const float2 s = S2[c * 64 + lane];
        a0.x += w * s.x; a0.y += w * s.y;
    }
    float2 acc;
    acc.x = (a0.x + a1.x) + (a2.x + a3.x);
    acc.y = (a0.y + a1.y) + (a2.y + a3.y);
    ((float2*)dst)[wave * 64 + lane] = acc;
}

// ---------------- launch ----------------

extern "C" void kernel_launch(void* const* d_in, const int* in_sizes, int n_in,
                              void* d_out, int out_size, void* d_ws, size_t ws_size,
                              hipStream_t stream) {
    const int*   fi   = (const int*)d_in[0];     // feat_indices [2, nnzf]
    const float* fv   = (const float*)d_in[1];   // feat_values  [nnzf]
    const int*   ai   = (const int*)d_in[2];     // adj_indices  [2, nedge]
    const float* av   = (const float*)d_in[3];   // adj_values   [nedge]
    const float* W    = (const float*)d_in[4];   // weight [512,128]
    const float* bias = (const float*)d_in[5];   // bias [1,128]
    float* out = (float*)d_out;

    const int nnzf  = in_sizes[1];
    const int nedge = in_sizes[3];
    const int* f_rows = fi;
    const int* f_cols = fi + nnzf;
    const int* a_rows = ai;
    const int* a_cols = ai + nedge;

    // bump-allocate workspace (256B aligned)
    char* wp = (char*)d_ws;
    auto balloc = [&](size_t bytes) -> char* {
        char* p = wp;
        wp += (bytes + 255) & ~(size_t)255;
        return p;
    };
    float* base_ws = (float*)balloc(sizeof(float) * (size_t)N_NODES * OUT_C);
    int*   f_rp    = (int*)balloc(4 * (size_t)(N_NODES + 1));
    int*   f_cur   = (int*)balloc(4 * (size_t)N_NODES);
    int*   f_ccol  = (int*)balloc(4 * (size_t)nnzf);
    float* f_cval  = (float*)balloc(4 * (size_t)nnzf);
    int*   a_rp    = (int*)balloc(4 * (size_t)(N_NODES + 1));
    int*   a_cur   = (int*)balloc(4 * (size_t)N_NODES);
    int*   a_ccol  = (int*)balloc(4 * (size_t)nedge);
    float* a_cval  = (float*)balloc(4 * (size_t)nedge);
    int*   blk     = (int*)balloc(4 * 1024);

    const int ZB = (N_NODES + 255) / 256;
    const int FB = (nnzf + 255) / 256;
    const int AB = (nedge + 255) / 256;
    const int RW = (N_NODES + 3) / 4;    // 4 waves (rows) per 256-thread block
    const int NB = (N_NODES + SCAN_CHUNK - 1) / SCAN_CHUNK;   // 49

    // ---- feature CSR ----
    zero_int_kernel<<<ZB, 256, 0, stream>>>(f_cur, N_NODES);
    count_rows_kernel<<<FB, 256, 0, stream>>>(f_rows, f_cur, nnzf);
    scan_blocksums_kernel<<<NB, SCAN_T, 0, stream>>>(f_cur, blk, N_NODES);
    scan_toplevel_kernel<<<1, 1024, 0, stream>>>(blk, NB, f_rp, N_NODES);
    scan_final_kernel<<<NB, SCAN_T, 0, stream>>>(f_cur, blk, f_rp, f_cur, N_NODES);
    scatter_coo_kernel<<<FB, 256, 0, stream>>>(f_rows, f_cols, fv, f_cur, f_ccol, f_cval, nnzf);

    // ---- adjacency CSR ----
    zero_int_kernel<<<ZB, 256, 0, stream>>>(a_cur, N_NODES);
    count_rows_kernel<<<AB, 256, 0, stream>>>(a_rows, a_cur, nedge);
    scan_blocksums_kernel<<<NB, SCAN_T, 0, stream>>>(a_cur, blk, N_NODES);
    scan_toplevel_kernel<<<1, 1024, 0, stream>>>(blk, NB, a_rp, N_NODES);
    scan_final_kernel<<<NB, SCAN_T, 0, stream>>>(a_cur, blk, a_rp, a_cur, N_NODES);
    scatter_coo_kernel<<<AB, 256, 0, stream>>>(a_rows, a_cols, av, a_cur, a_ccol, a_cval, nedge);

    // ---- compute: spmm -> d_out, adj -> ws, adj -> d_out ----
    spmm_feat_kernel<<<RW, 256, 0, stream>>>(f_rp, f_ccol, f_cval, W, bias, out, N_NODES);
    spmm_adj_kernel<<<RW, 256, 0, stream>>>(a_rp, a_ccol, a_cval, out, base_ws, N_NODES);
    spmm_adj_kernel<<<RW, 256, 0, stream>>>(a_rp, a_ccol, a_cval, base_ws, out, N_NODES);
}

// Round 3
// 664.391 us; speedup vs baseline: 1.9932x; 1.1655x over previous
//
#include <hip/hip_runtime.h>

#define N_NODES 100000
#define VROWS   200000          // virtual rows: [0,100000)=feat, [100000,200000)=adj
#define NGROUP  8               // XCD count
#define RPG     (VROWS / NGROUP)
#define OUT_C   128             // 64 lanes * float2

#define SCAN_T     256
#define SCAN_ITEMS 8
#define SCAN_CHUNK (SCAN_T * SCAN_ITEMS)   // 2048 elems per block

// ---------------- CSR build (concatenated feat+adj problem) ----------------

__global__ void zero_int_kernel(int* __restrict__ p, int n) {
    int i = blockIdx.x * blockDim.x + threadIdx.x;
    if (i < n) p[i] = 0;
}

// counts over virtual rows: i<nnzf -> feat row; else adj row + N_NODES
__global__ void count_all_kernel(const int* __restrict__ f_rows, const int* __restrict__ a_rows,
                                 int* __restrict__ counts, int nnzf, int ntot) {
    int i = blockIdx.x * blockDim.x + threadIdx.x;
    if (i < ntot) {
        int r = (i < nnzf) ? f_rows[i] : (a_rows[i - nnzf] + N_NODES);
        atomicAdd(&counts[r], 1);
    }
}

// Pass 1: per-block sums of counts
__global__ __launch_bounds__(SCAN_T) void scan_blocksums_kernel(
        const int* __restrict__ counts, int* __restrict__ blk, int n) {
    __shared__ int red[SCAN_T];
    const int t = threadIdx.x;
    const int base = blockIdx.x * SCAN_CHUNK + t * SCAN_ITEMS;
    int s = 0;
    #pragma unroll
    for (int k = 0; k < SCAN_ITEMS; ++k) {
        int idx = base + k;
        if (idx < n) s += counts[idx];
    }
    red[t] = s;
    __syncthreads();
    for (int off = SCAN_T / 2; off > 0; off >>= 1) {
        if (t < off) red[t] += red[t + off];
        __syncthreads();
    }
    if (t == 0) blk[blockIdx.x] = red[0];
}

// Pass 2: single block — exclusive scan of <=1024 block sums in place; row_ptr[n]=total
__global__ void scan_toplevel_kernel(int* __restrict__ blk, int nb,
                                     int* __restrict__ row_ptr, int n) {
    __shared__ int sh[1024];
    const int t = threadIdx.x;
    int v = (t < nb) ? blk[t] : 0;
    sh[t] = v;
    __syncthreads();
    for (int off = 1; off < 1024; off <<= 1) {
        int u = (t >= off) ? sh[t - off] : 0;
        __syncthreads();
        sh[t] += u;
        __syncthreads();
    }
    if (t < nb) blk[t] = sh[t] - v;         // exclusive prefix
    if (t == 1023) row_ptr[n] = sh[1023];   // grand total
}

// Pass 3: per-block exclusive scan + global offset; writes row_ptr and cursor.
// counts aliases cursor: each idx read (counts) then written (cursor) by same thread.
__global__ __launch_bounds__(SCAN_T) void scan_final_kernel(
        const int* __restrict__ counts, const int* __restrict__ blk,
        int* __restrict__ row_ptr, int* __restrict__ cursor, int n) {
    __shared__ int sh[SCAN_T];
    const int t = threadIdx.x;
    const int base = blockIdx.x * SCAN_CHUNK + t * SCAN_ITEMS;
    int loc[SCAN_ITEMS];
    int s = 0;
    #pragma unroll
    for (int k = 0; k < SCAN_ITEMS; ++k) {
        int idx = base + k;
        int c = (idx < n) ? counts[idx] : 0;
        loc[k] = s;
        s += c;
    }
    sh[t] = s;
    __syncthreads();
    for (int off = 1; off < SCAN_T; off <<= 1) {
        int u = (t >= off) ? sh[t - off] : 0;
        __syncthreads();
        sh[t] += u;
        __syncthreads();
    }
    const int thread_off = blk[blockIdx.x] + ((t == 0) ? 0 : sh[t - 1]);
    #pragma unroll
    for (int k = 0; k < SCAN_ITEMS; ++k) {
        int idx = base + k;
        if (idx < n) {
            int p = thread_off + loc[k];
            row_ptr[idx] = p;
            cursor[idx]  = p;
        }
    }
}

// XCD-partitioned scatter: group g = blockIdx%8 handles virtual rows [g*RPG,(g+1)*RPG).
// All of group g's writes land in one contiguous ~3.6MB region -> one XCD's L2
// assembles full 64B lines before writeback (vs 8-way partial-line churn).
__global__ __launch_bounds__(256) void scatter_part_kernel(
        const int* __restrict__ f_rows, const int* __restrict__ f_cols, const float* __restrict__ f_vals,
        const int* __restrict__ a_rows, const int* __restrict__ a_cols, const float* __restrict__ a_vals,
        int* __restrict__ cursor, int2* __restrict__ colval, int nnzf, int ntot) {
    const int g   = blockIdx.x & (NGROUP - 1);
    const int bg  = blockIdx.x >> 3;
    const int bpg = gridDim.x >> 3;
    const int lo = g * RPG, hi = lo + RPG;
    const int stride = bpg * 256;
    for (int i = bg * 256 + (int)threadIdx.x; i < ntot; i += stride) {
        int r;
        if (i < nnzf) r = f_rows[i];
        else          r = a_rows[i - nnzf] + N_NODES;
        if (r >= lo && r < hi) {
            int c; float v;
            if (i < nnzf) { c = f_cols[i];        v = f_vals[i]; }
            else          { c = a_cols[i - nnzf]; v = a_vals[i - nnzf]; }
            int p = atomicAdd(&cursor[r], 1);
            colval[p] = make_int2(c, __float_as_int(v));
        }
    }
}

// ---------------- SpMM: sparse [N, IN_C] @ dense weight [IN_C, 128] + bias + relu ----------------
// One 64-lane wave per output row; each lane owns a float2 slice of the 128 outputs.

__global__ __launch_bounds__(256) void spmm_feat_kernel(
        const int* __restrict__ row_ptr, const int2* __restrict__ colval,
        const float* __restrict__ W, const float* __restrict__ bias,
        float* __restrict__ out, int n) {
    const int wave = (blockIdx.x * blockDim.x + threadIdx.x) >> 6;
    const int lane = threadIdx.x & 63;
    if (wave >= n) return;
    const int beg = row_ptr[wave];
    const int end = row_ptr[wave + 1];
    const float2* __restrict__ W2 = (const float2*)W;
    float2 a0 = make_float2(0.f, 0.f), a1 = a0, a2 = a0, a3 = a0;
    int i = beg;
    for (; i + 3 < end; i += 4) {
        const int2 e0 = colval[i],     e1 = colval[i + 1];
        const int2 e2 = colval[i + 2], e3 = colval[i + 3];
        const float2 w0 = W2[e0.x * 64 + lane];
        const float2 w1 = W2[e1.x * 64 + lane];
        const float2 w2 = W2[e2.x * 64 + lane];
        const float2 w3 = W2[e3.x * 64 + lane];
        const float v0 = __int_as_float(e0.y), v1 = __int_as_float(e1.y);
        const float v2 = __int_as_float(e2.y), v3 = __int_as_float(e3.y);
        a0.x += v0 * w0.x; a0.y += v0 * w0.y;
        a1.x += v1 * w1.x; a1.y += v1 * w1.y;
        a2.x += v2 * w2.x; a2.y += v2 * w2.y;
        a3.x += v3 * w3.x; a3.y += v3 * w3.y;
    }
    for (; i < end; ++i) {
        const int2 e = colval[i];
        const float v = __int_as_float(e.y);
        const float2 w = W2[e.x * 64 + lane];
        a0.x += v * w.x; a0.y += v * w.y;
    }
    const float2 b = ((const float2*)bias)[lane];
    float2 acc;
    acc.x = fmaxf((a0.x + a1.x) + (a2.x + a3.x) + b.x, 0.f);
    acc.y = fmaxf((a0.y + a1.y) + (a2.y + a3.y) + b.y, 0.f);
    ((float2*)out)[wave * 64 + lane] = acc;
}

// ---------------- adjacency propagation: dst = A @ src ----------------

__global__ __launch_bounds__(256) void spmm_adj_kernel(
        const int* __restrict__ row_ptr, const int2* __restrict__ colval,
        const float* __restrict__ src, float* __restrict__ dst, int n) {
    const int wave = (blockIdx.x * blockDim.x + threadIdx.x) >> 6;
    const int lane = threadIdx.x & 63;
    if (wave >= n) return;
    const int beg = row_ptr[wave];
    const int end = row_ptr[wave + 1];
    const float2* __restrict__ S2 = (const float2*)src;
    float2 a0 = make_float2(0.f, 0.f), a1 = a0, a2 = a0, a3 = a0;
    int i = beg;
    for (; i + 3 < end; i += 4) {
        const int2 e0 = colval[i],     e1 = colval[i + 1];
        const int2 e2 = colval[i + 2], e3 = colval[i + 3];
        const float2 s0 = S2[e0.x * 64 + lane];
        const float2 s1 = S2[e1.x * 64 + lane];
        const float2 s2 = S2[e2.x * 64 + lane];
        const float2 s3 = S2[e3.x * 64 + lane];
        const float v0 = __int_as_float(e0.y), v1 = __int_as_float(e1.y);
        const float v2 = __int_as_float(e2.y), v3 = __int_as_float(e3.y);
        a0.x += v0 * s0.x; a0.y += v0 * s0.y;
        a1.x += v1 * s1.x; a1.y += v1 * s1.y;
        a2.x += v2 * s2.x; a2.y += v2 * s2.y;
        a3.x += v3 * s3.x; a3.y += v3 * s3.y;
    }
    for (; i < end; ++i) {
        const int2 e = colval[i];
        const float v = __int_as_float(e.y);
        const float2 s = S2[e.x * 64 + lane];
        a0.x += v * s.x; a0.y += v * s.y;
    }
    float2 acc;
    acc.x = (a0.x + a1.x) + (a2.x + a3.x);
    acc.y = (a0.y + a1.y) + (a2.y + a3.y);
    ((float2*)dst)[wave * 64 + lane] = acc;
}

// ---------------- launch ----------------

extern "C" void kernel_launch(void* const* d_in, const int* in_sizes, int n_in,
                              void* d_out, int out_size, void* d_ws, size_t ws_size,
                              hipStream_t stream) {
    const int*   fi   = (const int*)d_in[0];     // feat_indices [2, nnzf]
    const float* fv   = (const float*)d_in[1];   // feat_values  [nnzf]
    const int*   ai   = (const int*)d_in[2];     // adj_indices  [2, nedge]
    const float* av   = (const float*)d_in[3];   // adj_values   [nedge]
    const float* W    = (const float*)d_in[4];   // weight [512,128]
    const float* bias = (const float*)d_in[5];   // bias [1,128]
    float* out = (float*)d_out;

    const int nnzf  = in_sizes[1];
    const int nedge = in_sizes[3];
    const int ntot  = nnzf + nedge;
    const int* f_rows = fi;
    const int* f_cols = fi + nnzf;
    const int* a_rows = ai;
    const int* a_cols = ai + nedge;

    // bump-allocate workspace (256B aligned)
    char* wp = (char*)d_ws;
    auto balloc = [&](size_t bytes) -> char* {
        char* p = wp;
        wp += (bytes + 255) & ~(size_t)255;
        return p;
    };
    float* base_ws = (float*)balloc(sizeof(float) * (size_t)N_NODES * OUT_C);
    int*   rp      = (int*)balloc(4 * (size_t)(VROWS + 1));
    int*   cur     = (int*)balloc(4 * (size_t)VROWS);
    int2*  colval  = (int2*)balloc(8 * (size_t)ntot);
    int*   blk     = (int*)balloc(4 * 1024);

    const int ZB = (VROWS + 255) / 256;
    const int CB = (ntot + 255) / 256;
    const int RW = (N_NODES + 3) / 4;                         // 4 waves per 256-thread block
    const int NB = (VROWS + SCAN_CHUNK - 1) / SCAN_CHUNK;     // 98

    // ---- concatenated CSR build ----
    zero_int_kernel<<<ZB, 256, 0, stream>>>(cur, VROWS);
    count_all_kernel<<<CB, 256, 0, stream>>>(f_rows, a_rows, cur, nnzf, ntot);
    scan_blocksums_kernel<<<NB, SCAN_T, 0, stream>>>(cur, blk, VROWS);
    scan_toplevel_kernel<<<1, 1024, 0, stream>>>(blk, NB, rp, VROWS);
    scan_final_kernel<<<NB, SCAN_T, 0, stream>>>(cur, blk, rp, cur, VROWS);
    scatter_part_kernel<<<NGROUP * 2048, 256, 0, stream>>>(
        f_rows, f_cols, fv, a_rows, a_cols, av, cur, colval, nnzf, ntot);

    // ---- compute: spmm -> d_out, adj -> ws, adj -> d_out ----
    spmm_feat_kernel<<<RW, 256, 0, stream>>>(rp, colval, W, bias, out, N_NODES);
    spmm_adj_kernel<<<RW, 256, 0, stream>>>(rp + N_NODES, colval, out, base_ws, N_NODES);
    spmm_adj_kernel<<<RW, 256, 0, stream>>>(rp + N_NODES, colval, base_ws, out, N_NODES);
}

// Round 5
// 644.527 us; speedup vs baseline: 2.0546x; 1.0308x over previous
//
#include <hip/hip_runtime.h>

#define N_NODES 100000
#define VROWS   200000          // virtual rows: [0,100000)=feat, [100000,200000)=adj
#define NGROUP  8               // XCD count
#define RPG     (VROWS / NGROUP)
#define OUT_C   128             // 64 lanes * float2

#define SCAN_T     256
#define SCAN_ITEMS 8
#define SCAN_CHUNK (SCAN_T * SCAN_ITEMS)   // 2048 elems per block

static __device__ __forceinline__ unsigned short f2bf(float x) {
    unsigned u = __float_as_uint(x);
    return (unsigned short)((u + 0x7fffu + ((u >> 16) & 1u)) >> 16);
}
static __device__ __forceinline__ float bf2f(unsigned short h) {
    return __uint_as_float(((unsigned)h) << 16);
}

// nt load of a packed (col,val) element via long long (builtin rejects HIP vector types)
static __device__ __forceinline__ void nt_colval(const long long* p, int& c, float& v) {
    long long e = __builtin_nontemporal_load(p);
    c = (int)(e & 0xffffffffLL);
    v = __uint_as_float((unsigned)((unsigned long long)e >> 32));
}

// ---------------- CSR build (concatenated feat+adj problem) ----------------

__global__ void zero_int_kernel(int* __restrict__ p, int n) {
    int i = blockIdx.x * blockDim.x + threadIdx.x;
    if (i < n) p[i] = 0;
}

// XCD-partitioned count: group g = blockIdx%8 counts only its own row range.
// nt loads keep the 8x-re-read stream out of L2 (L3 serves the reuse), so the
// group's counts region (~100KB) stays L2-resident with no cross-XCD ping-pong.
__global__ __launch_bounds__(256) void count_part_kernel(
        const int* __restrict__ f_rows, const int* __restrict__ a_rows,
        int* __restrict__ counts, int nnzf, int nedge) {
    const int g   = blockIdx.x & (NGROUP - 1);
    const int bg  = blockIdx.x >> 3;
    const int bpg = gridDim.x >> 3;
    const int lo = g * RPG, hi = lo + RPG;
    const int stride = bpg * 256;
    for (int i = bg * 256 + (int)threadIdx.x; i < nnzf; i += stride) {
        int r = __builtin_nontemporal_load(f_rows + i);
        if (r >= lo && r < hi) atomicAdd(&counts[r], 1);
    }
    for (int i = bg * 256 + (int)threadIdx.x; i < nedge; i += stride) {
        int r = __builtin_nontemporal_load(a_rows + i) + N_NODES;
        if (r >= lo && r < hi) atomicAdd(&counts[r], 1);
    }
}

// Pass 1: per-block sums of counts
__global__ __launch_bounds__(SCAN_T) void scan_blocksums_kernel(
        const int* __restrict__ counts, int* __restrict__ blk, int n) {
    __shared__ int red[SCAN_T];
    const int t = threadIdx.x;
    const int base = blockIdx.x * SCAN_CHUNK + t * SCAN_ITEMS;
    int s = 0;
    #pragma unroll
    for (int k = 0; k < SCAN_ITEMS; ++k) {
        int idx = base + k;
        if (idx < n) s += counts[idx];
    }
    red[t] = s;
    __syncthreads();
    for (int off = SCAN_T / 2; off > 0; off >>= 1) {
        if (t < off) red[t] += red[t + off];
        __syncthreads();
    }
    if (t == 0) blk[blockIdx.x] = red[0];
}

// Pass 2: single block — exclusive scan of <=1024 block sums in place; row_ptr[n]=total
__global__ void scan_toplevel_kernel(int* __restrict__ blk, int nb,
                                     int* __restrict__ row_ptr, int n) {
    __shared__ int sh[1024];
    const int t = threadIdx.x;
    int v = (t < nb) ? blk[t] : 0;
    sh[t] = v;
    __syncthreads();
    for (int off = 1; off < 1024; off <<= 1) {
        int u = (t >= off) ? sh[t - off] : 0;
        __syncthreads();
        sh[t] += u;
        __syncthreads();
    }
    if (t < nb) blk[t] = sh[t] - v;         // exclusive prefix
    if (t == 1023) row_ptr[n] = sh[1023];   // grand total
}

// Pass 3: per-block exclusive scan + global offset; writes row_ptr and cursor.
// counts aliases cursor: each idx read (counts) then written (cursor) by same thread.
__global__ __launch_bounds__(SCAN_T) void scan_final_kernel(
        const int* __restrict__ counts, const int* __restrict__ blk,
        int* __restrict__ row_ptr, int* __restrict__ cursor, int n) {
    __shared__ int sh[SCAN_T];
    const int t = threadIdx.x;
    const int base = blockIdx.x * SCAN_CHUNK + t * SCAN_ITEMS;
    int loc[SCAN_ITEMS];
    int s = 0;
    #pragma unroll
    for (int k = 0; k < SCAN_ITEMS; ++k) {
        int idx = base + k;
        int c = (idx < n) ? counts[idx] : 0;
        loc[k] = s;
        s += c;
    }
    sh[t] = s;
    __syncthreads();
    for (int off = 1; off < SCAN_T; off <<= 1) {
        int u = (t >= off) ? sh[t - off] : 0;
        __syncthreads();
        sh[t] += u;
        __syncthreads();
    }
    const int thread_off = blk[blockIdx.x] + ((t == 0) ? 0 : sh[t - 1]);
    #pragma unroll
    for (int k = 0; k < SCAN_ITEMS; ++k) {
        int idx = base + k;
        if (idx < n) {
            int p = thread_off + loc[k];
            row_ptr[idx] = p;
            cursor[idx]  = p;
        }
    }
}

// XCD-partitioned scatter with nt input streams: group g's writes land in one
// contiguous ~3.6MB region of one XCD's L2; nt loads stop the stream from
// evicting partial write lines, so full 64B lines assemble before writeback.
__global__ __launch_bounds__(256) void scatter_part_kernel(
        const int* __restrict__ f_rows, const int* __restrict__ f_cols, const float* __restrict__ f_vals,
        const int* __restrict__ a_rows, const int* __restrict__ a_cols, const float* __restrict__ a_vals,
        int* __restrict__ cursor, long long* __restrict__ colval, int nnzf, int nedge) {
    const int g   = blockIdx.x & (NGROUP - 1);
    const int bg  = blockIdx.x >> 3;
    const int bpg = gridDim.x >> 3;
    const int lo = g * RPG, hi = lo + RPG;
    const int stride = bpg * 256;
    for (int i = bg * 256 + (int)threadIdx.x; i < nnzf; i += stride) {
        int r = __builtin_nontemporal_load(f_rows + i);
        if (r >= lo && r < hi) {
            int   c = __builtin_nontemporal_load(f_cols + i);
            float v = __builtin_nontemporal_load(f_vals + i);
            int p = atomicAdd(&cursor[r], 1);
            colval[p] = (long long)(unsigned)c | ((long long)(unsigned)__float_as_uint(v) << 32);
        }
    }
    for (int i = bg * 256 + (int)threadIdx.x; i < nedge; i += stride) {
        int r = __builtin_nontemporal_load(a_rows + i) + N_NODES;
        if (r >= lo && r < hi) {
            int   c = __builtin_nontemporal_load(a_cols + i);
            float v = __builtin_nontemporal_load(a_vals + i);
            int p = atomicAdd(&cursor[r], 1);
            colval[p] = (long long)(unsigned)c | ((long long)(unsigned)__float_as_uint(v) << 32);
        }
    }
}

// ---------------- SpMM: sparse [N, IN_C] @ dense weight [IN_C, 128] + bias + relu ----------------
// One 64-lane wave per output row; each lane owns a float2 slice of the 128 outputs.

__global__ __launch_bounds__(256) void spmm_feat_kernel(
        const int* __restrict__ row_ptr, const long long* __restrict__ colval,
        const float* __restrict__ W, const float* __restrict__ bias,
        float* __restrict__ out, int n) {
    const int wave = (blockIdx.x * blockDim.x + threadIdx.x) >> 6;
    const int lane = threadIdx.x & 63;
    if (wave >= n) return;
    const int beg = row_ptr[wave];
    const int end = row_ptr[wave + 1];
    const float2* __restrict__ W2 = (const float2*)W;
    float2 a0 = make_float2(0.f, 0.f), a1 = a0, a2 = a0, a3 = a0;
    int i = beg;
    for (; i + 3 < end; i += 4) {
        int c0, c1, c2, c3; float v0, v1, v2, v3;
        nt_colval(colval + i,     c0, v0);
        nt_colval(colval + i + 1, c1, v1);
        nt_colval(colval + i + 2, c2, v2);
        nt_colval(colval + i + 3, c3, v3);
        const float2 w0 = W2[c0 * 64 + lane];
        const float2 w1 = W2[c1 * 64 + lane];
        const float2 w2 = W2[c2 * 64 + lane];
        const float2 w3 = W2[c3 * 64 + lane];
        a0.x += v0 * w0.x; a0.y += v0 * w0.y;
        a1.x += v1 * w1.x; a1.y += v1 * w1.y;
        a2.x += v2 * w2.x; a2.y += v2 * w2.y;
        a3.x += v3 * w3.x; a3.y += v3 * w3.y;
    }
    for (; i < end; ++i) {
        int c; float v;
        nt_colval(colval + i, c, v);
        const float2 w = W2[c * 64 + lane];
        a0.x += v * w.x; a0.y += v * w.y;
    }
    const float2 b = ((const float2*)bias)[lane];
    float2 acc;
    acc.x = fmaxf((a0.x + a1.x) + (a2.x + a3.x) + b.x, 0.f);
    acc.y = fmaxf((a0.y + a1.y) + (a2.y + a3.y) + b.y, 0.f);
    ((float2*)out)[wave * 64 + lane] = acc;
}

// ---------------- adjacency pass 1: t1(bf16) = A @ base(f32) ----------------

__global__ __launch_bounds__(256) void spmm_adj_f32in_bf16out_kernel(
        const int* __restrict__ row_ptr, const long long* __restrict__ colval,
        const float* __restrict__ src, unsigned short* __restrict__ dst, int n) {
    const int wave = (blockIdx.x * blockDim.x + threadIdx.x) >> 6;
    const int lane = threadIdx.x & 63;
    if (wave >= n) return;
    const int beg = row_ptr[wave];
    const int end = row_ptr[wave + 1];
    const float2* __restrict__ S2 = (const float2*)src;
    float2 a0 = make_float2(0.f, 0.f), a1 = a0, a2 = a0, a3 = a0;
    int i = beg;
    for (; i + 3 < end; i += 4) {
        int c0, c1, c2, c3; float v0, v1, v2, v3;
        nt_colval(colval + i,     c0, v0);
        nt_colval(colval + i + 1, c1, v1);
        nt_colval(colval + i + 2, c2, v2);
        nt_colval(colval + i + 3, c3, v3);
        const float2 s0 = S2[c0 * 64 + lane];
        const float2 s1 = S2[c1 * 64 + lane];
        const float2 s2 = S2[c2 * 64 + lane];
        const float2 s3 = S2[c3 * 64 + lane];
        a0.x += v0 * s0.x; a0.y += v0 * s0.y;
        a1.x += v1 * s1.x; a1.y += v1 * s1.y;
        a2.x += v2 * s2.x; a2.y += v2 * s2.y;
        a3.x += v3 * s3.x; a3.y += v3 * s3.y;
    }
    for (; i < end; ++i) {
        int c; float v;
        nt_colval(colval + i, c, v);
        const float2 s = S2[c * 64 + lane];
        a0.x += v * s.x; a0.y += v * s.y;
    }
    float2 acc;
    acc.x = (a0.x + a1.x) + (a2.x + a3.x);
    acc.y = (a0.y + a1.y) + (a2.y + a3.y);
    ushort2 o;
    o.x = f2bf(acc.x);
    o.y = f2bf(acc.y);
    ((ushort2*)dst)[wave * 64 + lane] = o;
}

// ---------------- adjacency pass 2: out(f32) = A @ t1(bf16) ----------------

__global__ __launch_bounds__(256) void spmm_adj_bf16in_f32out_kernel(
        const int* __restrict__ row_ptr, const long long* __restrict__ colval,
        const unsigned short* __restrict__ src, float* __restrict__ dst, int n) {
    const int wave = (blockIdx.x * blockDim.x + threadIdx.x) >> 6;
    const int lane = threadIdx.x & 63;
    if (wave >= n) return;
    const int beg = row_ptr[wave];
    const int end = row_ptr[wave + 1];
    const unsigned* __restrict__ S2 = (const unsigned*)src;   // 2 bf16 packed per u32
    float2 a0 = make_float2(0.f, 0.f), a1 = a0, a2 = a0, a3 = a0;
    int i = beg;
    for (; i + 3 < end; i += 4) {
        int c0, c1, c2, c3; float v0, v1, v2, v3;
        nt_colval(colval + i,     c0, v0);
        nt_colval(colval + i + 1, c1, v1);
        nt_colval(colval + i + 2, c2, v2);
        nt_colval(colval + i + 3, c3, v3);
        const unsigned s0 = S2[c0 * 64 + lane];
        const unsigned s1 = S2[c1 * 64 + lane];
        const unsigned s2 = S2[c2 * 64 + lane];
        const unsigned s3 = S2[c3 * 64 + lane];
        a0.x += v0 * __uint_as_float(s0 << 16); a0.y += v0 * __uint_as_float(s0 & 0xffff0000u);
        a1.x += v1 * __uint_as_float(s1 << 16); a1.y += v1 * __uint_as_float(s1 & 0xffff0000u);
        a2.x += v2 * __uint_as_float(s2 << 16); a2.y += v2 * __uint_as_float(s2 & 0xffff0000u);
        a3.x += v3 * __uint_as_float(s3 << 16); a3.y += v3 * __uint_as_float(s3 & 0xffff0000u);
    }
    for (; i < end; ++i) {
        int c; float v;
        nt_colval(colval + i, c, v);
        const unsigned s = S2[c * 64 + lane];
        a0.x += v * __uint_as_float(s << 16); a0.y += v * __uint_as_float(s & 0xffff0000u);
    }
    float2 acc;
    acc.x = (a0.x + a1.x) + (a2.x + a3.x);
    acc.y = (a0.y + a1.y) + (a2.y + a3.y);
    ((float2*)dst)[wave * 64 + lane] = acc;
}

// ---------------- launch ----------------

extern "C" void kernel_launch(void* const* d_in, const int* in_sizes, int n_in,
                              void* d_out, int out_size, void* d_ws, size_t ws_size,
                              hipStream_t stream) {
    const int*   fi   = (const int*)d_in[0];     // feat_indices [2, nnzf]
    const float* fv   = (const float*)d_in[1];   // feat_values  [nnzf]
    const int*   ai   = (const int*)d_in[2];     // adj_indices  [2, nedge]
    const float* av   = (const float*)d_in[3];   // adj_values   [nedge]
    const float* W    = (const float*)d_in[4];   // weight [512,128]
    const float* bias = (const float*)d_in[5];   // bias [1,128]
    float* out = (float*)d_out;

    const int nnzf  = in_sizes[1];
    const int nedge = in_sizes[3];
    const int ntot  = nnzf + nedge;
    const int* f_rows = fi;
    const int* f_cols = fi + nnzf;
    const int* a_rows = ai;
    const int* a_cols = ai + nedge;

    // bump-allocate workspace (256B aligned)
    char* wp = (char*)d_ws;
    auto balloc = [&](size_t bytes) -> char* {
        char* p = wp;
        wp += (bytes + 255) & ~(size_t)255;
        return p;
    };
    unsigned short* t1 = (unsigned short*)balloc(2 * (size_t)N_NODES * OUT_C);
    int*       rp      = (int*)balloc(4 * (size_t)(VROWS + 1));
    int*       cur     = (int*)balloc(4 * (size_t)VROWS);
    long long* colval  = (long long*)balloc(8 * (size_t)ntot);
    int*       blk     = (int*)balloc(4 * 1024);

    const int ZB = (VROWS + 255) / 256;
    const int RW = (N_NODES + 3) / 4;                         // 4 waves per 256-thread block
    const int NB = (VROWS + SCAN_CHUNK - 1) / SCAN_CHUNK;     // 98

    // ---- concatenated CSR build ----
    zero_int_kernel<<<ZB, 256, 0, stream>>>(cur, VROWS);
    count_part_kernel<<<NGROUP * 2048, 256, 0, stream>>>(f_rows, a_rows, cur, nnzf, nedge);
    scan_blocksums_kernel<<<NB, SCAN_T, 0, stream>>>(cur, blk, VROWS);
    scan_toplevel_kernel<<<1, 1024, 0, stream>>>(blk, NB, rp, VROWS);
    scan_final_kernel<<<NB, SCAN_T, 0, stream>>>(cur, blk, rp, cur, VROWS);
    scatter_part_kernel<<<NGROUP * 2048, 256, 0, stream>>>(
        f_rows, f_cols, fv, a_rows, a_cols, av, cur, colval, nnzf, nedge);

    // ---- compute: spmm -> d_out(f32), adj -> t1(bf16), adj -> d_out(f32) ----
    spmm_feat_kernel<<<RW, 256, 0, stream>>>(rp, colval, W, bias, out, N_NODES);
    spmm_adj_f32in_bf16out_kernel<<<RW, 256, 0, stream>>>(rp + N_NODES, colval, out, t1, N_NODES);
    spmm_adj_bf16in_f32out_kernel<<<RW, 256, 0, stream>>>(rp + N_NODES, colval, t1, out, N_NODES);
}

// Round 6
// 610.747 us; speedup vs baseline: 2.1682x; 1.0553x over previous
//
#include <hip/hip_runtime.h>

#define N_NODES 100000
#define VROWS   200000          // virtual rows: [0,100000)=feat, [100000,200000)=adj
#define NGROUP  8               // XCD count (blockIdx%8 -> XCD heuristic)
#define BSHIFT  8
#define BROWS   256             // rows per bucket
#define NBUCK   ((VROWS + BROWS - 1) / BROWS)   // 782
#define SUBCAP  1024            // staged elems per (bucket,group); mean 576, std 24

static __device__ __forceinline__ unsigned short f2bf(float x) {
    unsigned u = __float_as_uint(x);
    return (unsigned short)((u + 0x7fffu + ((u >> 16) & 1u)) >> 16);
}

// nt load of a packed (col,val) element via long long (builtin rejects HIP vector types)
static __device__ __forceinline__ void nt_colval(const long long* p, int& c, float& v) {
    long long e = __builtin_nontemporal_load(p);
    c = (int)(e & 0xffffffffLL);
    v = __uint_as_float((unsigned)((unsigned long long)e >> 32));
}

// ---------------- CSR build: 2-phase bucket sort ----------------

__global__ void zero_int_kernel(int* __restrict__ p, int n) {
    int i = blockIdx.x * blockDim.x + threadIdx.x;
    if (i < n) p[i] = 0;
}

// Phase A: single-pass binning. Element -> bucket (vrow>>8), sub-region g=blockIdx&7
// (one XCD per sub-region). The per-(b,g) cursor makes writes time-ordered
// contiguous, so 64B lines assemble in that XCD's L2 before writeback.
// Payload: lo32 = col(17b) | rowlocal(8b)<<17 ; hi32 = val bits.
__global__ __launch_bounds__(256) void bin_kernel(
        const int* __restrict__ f_rows, const int* __restrict__ f_cols, const float* __restrict__ f_vals,
        const int* __restrict__ a_rows, const int* __restrict__ a_cols, const float* __restrict__ a_vals,
        int* __restrict__ cur, long long* __restrict__ staging, int nnzf, int nedge) {
    const int g = blockIdx.x & (NGROUP - 1);
    const int tid0 = blockIdx.x * 256 + (int)threadIdx.x;
    const int stride = gridDim.x * 256;
    for (int i = tid0; i < nnzf; i += stride) {
        int   r = __builtin_nontemporal_load(f_rows + i);
        int   c = __builtin_nontemporal_load(f_cols + i);
        float v = __builtin_nontemporal_load(f_vals + i);
        int cell = (r >> BSHIFT) * NGROUP + g;
        int p = atomicAdd(&cur[cell], 1);
        if (p < SUBCAP) {
            unsigned lo = (unsigned)c | ((unsigned)(r & (BROWS - 1)) << 17);
            staging[(size_t)cell * SUBCAP + p] =
                (long long)lo | ((long long)(unsigned)__float_as_uint(v) << 32);
        }
    }
    for (int i = tid0; i < nedge; i += stride) {
        int   r = __builtin_nontemporal_load(a_rows + i) + N_NODES;
        int   c = __builtin_nontemporal_load(a_cols + i);
        float v = __builtin_nontemporal_load(a_vals + i);
        int cell = (r >> BSHIFT) * NGROUP + g;
        int p = atomicAdd(&cur[cell], 1);
        if (p < SUBCAP) {
            unsigned lo = (unsigned)c | ((unsigned)(r & (BROWS - 1)) << 17);
            staging[(size_t)cell * SUBCAP + p] =
                (long long)lo | ((long long)(unsigned)__float_as_uint(v) << 32);
        }
    }
}

// Bucket-level exclusive scan (1 block, 1024 threads; NBUCK=782 fits).
__global__ void bucket_scan_kernel(const int* __restrict__ cur, int* __restrict__ bases,
                                   int* __restrict__ rp) {
    __shared__ int sh[1024];
    const int t = threadIdx.x;
    int tot = 0;
    if (t < NBUCK) {
        #pragma unroll
        for (int g = 0; g < NGROUP; ++g) tot += min(cur[t * NGROUP + g], SUBCAP);
    }
    sh[t] = tot;
    __syncthreads();
    for (int off = 1; off < 1024; off <<= 1) {
        int u = (t >= off) ? sh[t - off] : 0;
        __syncthreads();
        sh[t] += u;
        __syncthreads();
    }
    if (t < NBUCK) bases[t] = sh[t] - tot;      // exclusive prefix
    if (t == NBUCK - 1) rp[VROWS] = sh[t];      // grand total sentinel
}

// Phase B: one block per bucket. Stream the 8 staged sub-segments twice:
// count rows in LDS -> 256-wide scan -> write row_ptr -> place into final colval.
// Final colval writes land in one ~40KB bucket window -> full-line assembly.
__global__ __launch_bounds__(256) void sort_kernel(
        const int* __restrict__ cur, const int* __restrict__ bases,
        const long long* __restrict__ staging, long long* __restrict__ colval,
        int* __restrict__ rp) {
    const int b = blockIdx.x;
    const int t = threadIdx.x;
    __shared__ int cnt[BROWS];
    __shared__ int offs[BROWS];
    __shared__ int segc[NGROUP];
    cnt[t] = 0;
    if (t < NGROUP) segc[t] = min(cur[b * NGROUP + t], SUBCAP);
    __syncthreads();
    const long long* sbase = staging + (size_t)b * NGROUP * SUBCAP;
    // pass 1: count rows
    for (int g = 0; g < NGROUP; ++g) {
        const int n = segc[g];
        const long long* seg = sbase + (size_t)g * SUBCAP;
        for (int j = t; j < n; j += 256) {
            unsigned lo = (unsigned)(seg[j] & 0xffffffffLL);
            atomicAdd(&cnt[(lo >> 17) & (BROWS - 1)], 1);
        }
    }
    __syncthreads();
    // exclusive scan of cnt (Hillis-Steele over 256)
    int v = cnt[t];
    offs[t] = v;
    __syncthreads();
    for (int o = 1; o < BROWS; o <<= 1) {
        int u = (t >= o) ? offs[t - o] : 0;
        __syncthreads();
        offs[t] += u;
        __syncthreads();
    }
    const int excl = offs[t] - v;    // each thread reads only its own slot
    offs[t] = excl;                  // becomes the placement cursor
    const int base = bases[b];
    const int row = (b << BSHIFT) + t;
    if (row < VROWS) rp[row] = base + excl;
    __syncthreads();
    // pass 2: place (strip rowlocal from lo, keep col|valbits)
    for (int g = 0; g < NGROUP; ++g) {
        const int n = segc[g];
        const long long* seg = sbase + (size_t)g * SUBCAP;
        for (int j = t; j < n; j += 256) {
            long long e = seg[j];
            unsigned lo = (unsigned)(e & 0xffffffffLL);
            int rl = (lo >> 17) & (BROWS - 1);
            int p = atomicAdd(&offs[rl], 1);
            colval[base + p] = (long long)(lo & 0x1ffffu) | (e & 0xffffffff00000000LL);
        }
    }
}

// ---------------- SpMM: sparse [N,512] @ W[512,128] + bias + relu -> bf16 base ----------------
// One wave per row; each lane owns a float2 slice of the 128 outputs.

__global__ __launch_bounds__(256) void spmm_feat_kernel(
        const int* __restrict__ row_ptr, const long long* __restrict__ colval,
        const float* __restrict__ W, const float* __restrict__ bias,
        unsigned short* __restrict__ base_bf, int n) {
    const int wave = (blockIdx.x * blockDim.x + threadIdx.x) >> 6;
    const int lane = threadIdx.x & 63;
    if (wave >= n) return;
    const int beg = row_ptr[wave];
    const int end = row_ptr[wave + 1];
    const float2* __restrict__ W2 = (const float2*)W;
    float2 a0 = make_float2(0.f, 0.f), a1 = a0, a2 = a0, a3 = a0;
    int i = beg;
    for (; i + 3 < end; i += 4) {
        int c0, c1, c2, c3; float v0, v1, v2, v3;
        nt_colval(colval + i,     c0, v0);
        nt_colval(colval + i + 1, c1, v1);
        nt_colval(colval + i + 2, c2, v2);
        nt_colval(colval + i + 3, c3, v3);
        const float2 w0 = W2[c0 * 64 + lane];
        const float2 w1 = W2[c1 * 64 + lane];
        const float2 w2 = W2[c2 * 64 + lane];
        const float2 w3 = W2[c3 * 64 + lane];
        a0.x += v0 * w0.x; a0.y += v0 * w0.y;
        a1.x += v1 * w1.x; a1.y += v1 * w1.y;
        a2.x += v2 * w2.x; a2.y += v2 * w2.y;
        a3.x += v3 * w3.x; a3.y += v3 * w3.y;
    }
    for (; i < end; ++i) {
        int c; float v;
        nt_colval(colval + i, c, v);
        const float2 w = W2[c * 64 + lane];
        a0.x += v * w.x; a0.y += v * w.y;
    }
    const float2 b = ((const float2*)bias)[lane];
    float ax = fmaxf((a0.x + a1.x) + (a2.x + a3.x) + b.x, 0.f);
    float ay = fmaxf((a0.y + a1.y) + (a2.y + a3.y) + b.y, 0.f);
    ushort2 o;
    o.x = f2bf(ax);
    o.y = f2bf(ay);
    ((ushort2*)base_bf)[wave * 64 + lane] = o;
}

// ---------------- adjacency pass: dst = A @ src, bf16 in / bf16 out ----------------

__global__ __launch_bounds__(256) void spmm_adj_bf_bf_kernel(
        const int* __restrict__ row_ptr, const long long* __restrict__ colval,
        const unsigned* __restrict__ src, unsigned short* __restrict__ dst, int n) {
    const int wave = (blockIdx.x * blockDim.x + threadIdx.x) >> 6;
    const int lane = threadIdx.x & 63;
    if (wave >= n) return;
    const int beg = row_ptr[wave];
    const int end = row_ptr[wave + 1];
    float2 a0 = make_float2(0.f, 0.f), a1 = a0, a2 = a0, a3 = a0;
    int i = beg;
    for (; i + 3 < end; i += 4) {
        int c0, c1, c2, c3; float v0, v1, v2, v3;
        nt_colval(colval + i,     c0, v0);
        nt_colval(colval + i + 1, c1, v1);
        nt_colval(colval + i + 2, c2, v2);
        nt_colval(colval + i + 3, c3, v3);
        const unsigned s0 = src[c0 * 64 + lane];
        const unsigned s1 = src[c1 * 64 + lane];
        const unsigned s2 = src[c2 * 64 + lane];
        const unsigned s3 = src[c3 * 64 + lane];
        a0.x += v0 * __uint_as_float(s0 << 16); a0.y += v0 * __uint_as_float(s0 & 0xffff0000u);
        a1.x += v1 * __uint_as_float(s1 << 16); a1.y += v1 * __uint_as_float(s1 & 0xffff0000u);
        a2.x += v2 * __uint_as_float(s2 << 16); a2.y += v2 * __uint_as_float(s2 & 0xffff0000u);
        a3.x += v3 * __uint_as_float(s3 << 16); a3.y += v3 * __uint_as_float(s3 & 0xffff0000u);
    }
    for (; i < end; ++i) {
        int c; float v;
        nt_colval(colval + i, c, v);
        const unsigned s = src[c * 64 + lane];
        a0.x += v * __uint_as_float(s << 16); a0.y += v * __uint_as_float(s & 0xffff0000u);
    }
    float ax = (a0.x + a1.x) + (a2.x + a3.x);
    float ay = (a0.y + a1.y) + (a2.y + a3.y);
    ushort2 o;
    o.x = f2bf(ax);
    o.y = f2bf(ay);
    ((ushort2*)dst)[wave * 64 + lane] = o;
}

// ---------------- adjacency pass: dst = A @ src, bf16 in / f32 out ----------------

__global__ __launch_bounds__(256) void spmm_adj_bf_f32_kernel(
        const int* __restrict__ row_ptr, const long long* __restrict__ colval,
        const unsigned* __restrict__ src, float* __restrict__ dst, int n) {
    const int wave = (blockIdx.x * blockDim.x + threadIdx.x) >> 6;
    const int lane = threadIdx.x & 63;
    if (wave >= n) return;
    const int beg = row_ptr[wave];
    const int end = row_ptr[wave + 1];
    float2 a0 = make_float2(0.f, 0.f), a1 = a0, a2 = a0, a3 = a0;
    int i = beg;
    for (; i + 3 < end; i += 4) {
        int c0, c1, c2, c3; float v0, v1, v2, v3;
        nt_colval(colval + i,     c0, v0);
        nt_colval(colval + i + 1, c1, v1);
        nt_colval(colval + i + 2, c2, v2);
        nt_colval(colval + i + 3, c3, v3);
        const unsigned s0 = src[c0 * 64 + lane];
        const unsigned s1 = src[c1 * 64 + lane];
        const unsigned s2 = src[c2 * 64 + lane];
        const unsigned s3 = src[c3 * 64 + lane];
        a0.x += v0 * __uint_as_float(s0 << 16); a0.y += v0 * __uint_as_float(s0 & 0xffff0000u);
        a1.x += v1 * __uint_as_float(s1 << 16); a1.y += v1 * __uint_as_float(s1 & 0xffff0000u);
        a2.x += v2 * __uint_as_float(s2 << 16); a2.y += v2 * __uint_as_float(s2 & 0xffff0000u);
        a3.x += v3 * __uint_as_float(s3 << 16); a3.y += v3 * __uint_as_float(s3 & 0xffff0000u);
    }
    for (; i < end; ++i) {
        int c; float v;
        nt_colval(colval + i, c, v);
        const unsigned s = src[c * 64 + lane];
        a0.x += v * __uint_as_float(s << 16); a0.y += v * __uint_as_float(s & 0xffff0000u);
    }
    float2 acc;
    acc.x = (a0.x + a1.x) + (a2.x + a3.x);
    acc.y = (a0.y + a1.y) + (a2.y + a3.y);
    ((float2*)dst)[wave * 64 + lane] = acc;
}

// ---------------- launch ----------------

extern "C" void kernel_launch(void* const* d_in, const int* in_sizes, int n_in,
                              void* d_out, int out_size, void* d_ws, size_t ws_size,
                              hipStream_t stream) {
    const int*   fi   = (const int*)d_in[0];     // feat_indices [2, nnzf]
    const float* fv   = (const float*)d_in[1];   // feat_values  [nnzf]
    const int*   ai   = (const int*)d_in[2];     // adj_indices  [2, nedge]
    const float* av   = (const float*)d_in[3];   // adj_values   [nedge]
    const float* W    = (const float*)d_in[4];   // weight [512,128]
    const float* bias = (const float*)d_in[5];   // bias [1,128]
    float* out = (float*)d_out;

    const int nnzf  = in_sizes[1];
    const int nedge = in_sizes[3];
    const int ntot  = nnzf + nedge;
    const int* f_rows = fi;
    const int* f_cols = fi + nnzf;
    const int* a_rows = ai;
    const int* a_cols = ai + nedge;

    // bump-allocate workspace (256B aligned)
    char* wp = (char*)d_ws;
    auto balloc = [&](size_t bytes) -> char* {
        char* p = wp;
        wp += (bytes + 255) & ~(size_t)255;
        return p;
    };
    // staging (51.2MB) is dead after sort_kernel; base_bf + t1 (25.6MB each) overlay it.
    long long* staging = (long long*)balloc(8ull * NBUCK * NGROUP * SUBCAP);
    unsigned short* base_bf = (unsigned short*)staging;
    unsigned short* t1 = (unsigned short*)((char*)staging + 2ull * N_NODES * 128);
    long long* colval = (long long*)balloc(8ull * (size_t)ntot);
    int* rp    = (int*)balloc(4ull * (VROWS + 1));
    int* cur   = (int*)balloc(4ull * NBUCK * NGROUP);
    int* bases = (int*)balloc(4ull * NBUCK);

    const int NCELL = NBUCK * NGROUP;
    const int RW = (N_NODES + 3) / 4;    // 4 waves (rows) per 256-thread block

    // ---- CSR build: bin -> bucket scan -> per-bucket sort ----
    zero_int_kernel<<<(NCELL + 255) / 256, 256, 0, stream>>>(cur, NCELL);
    bin_kernel<<<2048, 256, 0, stream>>>(f_rows, f_cols, fv, a_rows, a_cols, av,
                                         cur, staging, nnzf, nedge);
    bucket_scan_kernel<<<1, 1024, 0, stream>>>(cur, bases, rp);
    sort_kernel<<<NBUCK, 256, 0, stream>>>(cur, bases, staging, colval, rp);

    // ---- compute: feat -> base_bf(bf16), adj -> t1(bf16), adj -> out(f32) ----
    spmm_feat_kernel<<<RW, 256, 0, stream>>>(rp, colval, W, bias, base_bf, N_NODES);
    spmm_adj_bf_bf_kernel<<<RW, 256, 0, stream>>>(rp + N_NODES, colval,
                                                  (const unsigned*)base_bf, t1, N_NODES);
    spmm_adj_bf_f32_kernel<<<RW, 256, 0, stream>>>(rp + N_NODES, colval,
                                                   (const unsigned*)t1, out, N_NODES);
}